// Round 5
// baseline (591.473 us; speedup 1.0000x reference)
//
#include <hip/hip_runtime.h>
#include <cstdint>

#define ENC_DEPTH 8
#define RPB 64
#define THREADS 256

typedef __attribute__((ext_vector_type(8))) short bf16x8;
typedef __attribute__((ext_vector_type(4))) float f32x4;

union bf8u { bf16x8 v; unsigned u[4]; };

__device__ __forceinline__ unsigned cvtpk(float lo, float hi) {
    unsigned r;
    asm volatile("v_cvt_pk_bf16_f32 %0, %1, %2" : "=v"(r) : "v"(lo), "v"(hi));
    return r;
}
__device__ __forceinline__ float bf2f(unsigned short h) {
    union { unsigned u; float f; } v; v.u = ((unsigned)h) << 16;
    return v.f;
}
__device__ __forceinline__ float clamp01(float x) { return fminf(fmaxf(x, 0.f), 1.f); }

// Pre-pass: W1 f32 [1024][64] row-major -> W1T bf16 [col][k] = [64][1024] (128 KB).
__global__ void w1t_pre(const float* __restrict__ W1, unsigned short* __restrict__ W1T) {
    int tid = blockIdx.x * 256 + threadIdx.x;       // 8192 threads
    int col = tid >> 7, kb = tid & 127;             // col in [0,64), kb in [0,128)
    const float* src = W1 + (size_t)kb * 512 + col; // W1[(kb*8+j)*64 + col]
    bf8u r;
    #pragma unroll
    for (int j = 0; j < 4; ++j)
        r.u[j] = cvtpk(src[(2 * j) * 64], src[(2 * j + 1) * 64]);
    *(bf16x8*)(W1T + (size_t)col * 1024 + kb * 8) = r.v;
}

// Wave-autonomous design: 4 waves/block, each wave owns 16 rays end-to-end.
// - corners_s/feat_s are wave-PRIVATE row ranges -> no cross-wave LDS sharing
// - MFMA B-fragments read directly from global W1T (L1/L2-hot, 128 KB)
// - ZERO s_barrier in the kernel; only wave-internal s_waitcnt lgkmcnt(0)
// LDS = 2 x 17408 = 34816 B -> 4 blocks/CU; VGPR cap 128 -> 16 indep waves/CU.
template<bool GW>
__global__ __launch_bounds__(THREADS, 4) void nbvh_kernel(
    const float* __restrict__ orig, const float* __restrict__ endp,
    const int* __restrict__ hist, const float* __restrict__ nodes_min,
    const float* __restrict__ nodes_extent, const float* __restrict__ emb,
    const float* __restrict__ W1, const unsigned short* __restrict__ W1T,
    const float* __restrict__ W2, const float* __restrict__ W3,
    float* __restrict__ out)
{
    __shared__ __align__(16) unsigned short corners_s[64 * 136];
    __shared__ __align__(16) unsigned short feat_s[64 * 136];

    const int t = threadIdx.x;
    const int wave = t >> 6, lane = t & 63;
    const int c = lane & 15;         // ray within wave
    const int s = lane >> 4;         // sub-role 0..3
    const int ray = wave * 16 + c;   // block-local ray
    const int r0 = blockIdx.x * RPB;
    const int gray = r0 + ray;

    const int* hrow_g = hist + (size_t)gray * ENC_DEPTH;

    const float* opr = orig + (size_t)gray * 3;
    const float* epr = endp + (size_t)gray * 3;
    float oex = opr[0], oey = opr[1], oez = opr[2];
    float eex = epr[0], eey = epr[1], eez = epr[2];

    // ---- depth-0 gather prefetch: this lane owns corners {2s, 2s+1} (32 floats) ----
    int node0 = hrow_g[0];
    const float4* eb = (const float4*)(emb + ((size_t)node0 << 7)) + s * 8;
    float4 p0 = eb[0], p1 = eb[1], p2 = eb[2], p3 = eb[3];
    float4 p4 = eb[4], p5 = eb[5], p6 = eb[6], p7 = eb[7];
    float nm0 = nodes_min[node0 * 3], nm1 = nodes_min[node0 * 3 + 1], nm2 = nodes_min[node0 * 3 + 2];
    float ex0 = nodes_extent[node0 * 3], ex1 = nodes_extent[node0 * 3 + 1], ex2 = nodes_extent[node0 * 3 + 2];

    f32x4 acc0 = {0.f,0.f,0.f,0.f}, acc1 = {0.f,0.f,0.f,0.f};
    f32x4 acc2 = {0.f,0.f,0.f,0.f}, acc3 = {0.f,0.f,0.f,0.f};

    const float ttA = (float)s * (1.0f / 7.0f);
    const float ttB = (float)(s + 4) * (1.0f / 7.0f);

    for (int d = 0; d < ENC_DEPTH; ++d) {
        // ---- (1) stage corners k-major from prefetch regs: 4 ds_write_b128 ----
        {
            bf8u w0, w1v, w2v, w3v;
            w0.u[0] = cvtpk(p0.x, p0.y); w0.u[1] = cvtpk(p0.z, p0.w);
            w0.u[2] = cvtpk(p1.x, p1.y); w0.u[3] = cvtpk(p1.z, p1.w);
            w1v.u[0] = cvtpk(p2.x, p2.y); w1v.u[1] = cvtpk(p2.z, p2.w);
            w1v.u[2] = cvtpk(p3.x, p3.y); w1v.u[3] = cvtpk(p3.z, p3.w);
            w2v.u[0] = cvtpk(p4.x, p4.y); w2v.u[1] = cvtpk(p4.z, p4.w);
            w2v.u[2] = cvtpk(p5.x, p5.y); w2v.u[3] = cvtpk(p5.z, p5.w);
            w3v.u[0] = cvtpk(p6.x, p6.y); w3v.u[1] = cvtpk(p6.z, p6.w);
            w3v.u[2] = cvtpk(p7.x, p7.y); w3v.u[3] = cvtpk(p7.z, p7.w);
            unsigned short* cbp = corners_s + ray * 136 + s * 32;  // corners 2s,2s+1
            *(bf16x8*)cbp        = w0.v;
            *(bf16x8*)(cbp + 8)  = w1v.v;
            *(bf16x8*)(cbp + 16) = w2v.v;
            *(bf16x8*)(cbp + 24) = w3v.v;
        }

        // ---- (2) issue next-depth gather prefetch (in flight across A2) ----
        float nn0 = nm0, nn1 = nm1, nn2 = nm2, en0 = ex0, en1 = ex1, en2 = ex2;
        if (d < ENC_DEPTH - 1) {
            int node1 = hrow_g[d + 1];
            const float4* eb2 = (const float4*)(emb + ((size_t)node1 << 7)) + s * 8;
            p0 = eb2[0]; p1 = eb2[1]; p2 = eb2[2]; p3 = eb2[3];
            p4 = eb2[4]; p5 = eb2[5]; p6 = eb2[6]; p7 = eb2[7];
            nn0 = nodes_min[node1 * 3]; nn1 = nodes_min[node1 * 3 + 1]; nn2 = nodes_min[node1 * 3 + 2];
            en0 = nodes_extent[node1 * 3]; en1 = nodes_extent[node1 * 3 + 1]; en2 = nodes_extent[node1 * 3 + 2];
        }

        // ---- (3) wave-internal visibility of corners ----
        asm volatile("s_waitcnt lgkmcnt(0)" ::: "memory");
        __builtin_amdgcn_sched_barrier(0);

        // ---- (4) A2: shared setup, then two (ray, p) pairs: p = s and p = s+4 ----
        {
            float rx = __builtin_amdgcn_rcpf(ex0);
            float ry = __builtin_amdgcn_rcpf(ex1);
            float rz = __builtin_amdgcn_rcpf(ex2);
            float po0 = clamp01((oex - nm0) * rx);
            float po1 = clamp01((oey - nm1) * ry);
            float po2 = clamp01((oez - nm2) * rz);
            float pe0 = clamp01((eex - nm0) * rx);
            float pe1 = clamp01((eey - nm1) * ry);
            float pe2 = clamp01((eez - nm2) * rz);
            float d0 = pe0 - po0, d1 = pe1 - po1, d2 = pe2 - po2;
            const unsigned short* cbase = corners_s + ray * 136;

            #pragma unroll
            for (int pr = 0; pr < 2; ++pr) {
                float ttv = pr ? ttB : ttA;
                float x = po0 + d0 * ttv;
                float y = po1 + d1 * ttv;
                float z = po2 + d2 * ttv;
                float ox = 1.f - x, oy = 1.f - y, oz = 1.f - z;
                float w[8];
                w[0] = ox * oy * oz;  w[1] = x * oy * oz;
                w[2] = ox * y * oz;   w[3] = ox * oy * z;
                w[4] = x * oy * z;    w[5] = ox * y * z;
                w[6] = x * y * oz;    w[7] = x * y * z;
                float fa[16];
                #pragma unroll
                for (int f = 0; f < 16; ++f) fa[f] = 0.f;
                #pragma unroll
                for (int k = 0; k < 8; ++k) {
                    bf16x8 cv0 = *(const bf16x8*)(cbase + (k << 4));
                    bf16x8 cv1 = *(const bf16x8*)(cbase + (k << 4) + 8);
                    #pragma unroll
                    for (int f = 0; f < 8; ++f) {
                        fa[f]     = fmaf(w[k], bf2f((unsigned short)cv0[f]), fa[f]);
                        fa[f + 8] = fmaf(w[k], bf2f((unsigned short)cv1[f]), fa[f + 8]);
                    }
                }
                bf8u fv0, fv1;
                #pragma unroll
                for (int j = 0; j < 4; ++j) {
                    fv0.u[j] = cvtpk(fa[2 * j], fa[2 * j + 1]);
                    fv1.u[j] = cvtpk(fa[8 + 2 * j], fa[9 + 2 * j]);
                }
                unsigned short* fbp = feat_s + ray * 136 + ((pr ? s + 4 : s) << 4);
                *(bf16x8*)fbp = fv0.v;
                *(bf16x8*)(fbp + 8) = fv1.v;
            }
        }

        // ---- (5) wave-internal visibility of feat ----
        asm volatile("s_waitcnt lgkmcnt(0)" ::: "memory");
        __builtin_amdgcn_sched_barrier(0);

        // ---- (6) MFMA: A from own feat rows, B direct from global W1T ----
        #pragma unroll
        for (int kk = 0; kk < 4; ++kk) {
            bf16x8 af = *(const bf16x8*)(feat_s + ray * 136 + kk * 32 + s * 8);
            bf16x8 b0, b1, b2, b3;
            if constexpr (GW) {
                const unsigned short* wb = W1T + (size_t)c * 1024 + d * 128 + kk * 32 + s * 8;
                b0 = *(const bf16x8*)wb;
                b1 = *(const bf16x8*)(wb + 16 * 1024);
                b2 = *(const bf16x8*)(wb + 32 * 1024);
                b3 = *(const bf16x8*)(wb + 48 * 1024);
            } else {
                const float* wsrc = W1 + (size_t)(d * 128 + kk * 32 + s * 8) * 64 + c;
                bf8u t0, t1, t2, t3;
                #pragma unroll
                for (int j = 0; j < 4; ++j) {
                    t0.u[j] = cvtpk(wsrc[(2*j)*64],      wsrc[(2*j+1)*64]);
                    t1.u[j] = cvtpk(wsrc[(2*j)*64 + 16], wsrc[(2*j+1)*64 + 16]);
                    t2.u[j] = cvtpk(wsrc[(2*j)*64 + 32], wsrc[(2*j+1)*64 + 32]);
                    t3.u[j] = cvtpk(wsrc[(2*j)*64 + 48], wsrc[(2*j+1)*64 + 48]);
                }
                b0 = t0.v; b1 = t1.v; b2 = t2.v; b3 = t3.v;
            }
            acc0 = __builtin_amdgcn_mfma_f32_16x16x32_bf16(af, b0, acc0, 0, 0, 0);
            acc1 = __builtin_amdgcn_mfma_f32_16x16x32_bf16(af, b1, acc1, 0, 0, 0);
            acc2 = __builtin_amdgcn_mfma_f32_16x16x32_bf16(af, b2, acc2, 0, 0, 0);
            acc3 = __builtin_amdgcn_mfma_f32_16x16x32_bf16(af, b3, acc3, 0, 0, 0);
        }

        nm0 = nn0; nm1 = nn1; nm2 = nn2;
        ex0 = en0; ex1 = en1; ex2 = en2;
    }

    // ---- h1 = relu(GEMM1) -> feat region f32 [64][68], wave-private rows ----
    float* h1s = (float*)feat_s;
    {
        int rb = wave * 16 + (s << 2);
        #pragma unroll
        for (int r = 0; r < 4; ++r) {
            h1s[(rb + r) * 68 + 0  + c] = fmaxf(acc0[r], 0.f);
            h1s[(rb + r) * 68 + 16 + c] = fmaxf(acc1[r], 0.f);
            h1s[(rb + r) * 68 + 32 + c] = fmaxf(acc2[r], 0.f);
            h1s[(rb + r) * 68 + 48 + c] = fmaxf(acc3[r], 0.f);
        }
    }
    asm volatile("s_waitcnt lgkmcnt(0)" ::: "memory");
    __builtin_amdgcn_sched_barrier(0);

    // ---- GEMM2: h2 = relu(h1 @ W2). lane: row c, cols [16s,16s+16). W2 from global (L1-hot) ----
    float* h2s = (float*)corners_s;
    {
        float sa[16];
        #pragma unroll
        for (int j = 0; j < 16; ++j) sa[j] = 0.f;
        const float* hr = h1s + (size_t)(wave * 16 + c) * 68;
        #pragma unroll
        for (int k4 = 0; k4 < 16; ++k4) {
            float4 hv = *(const float4*)(hr + (k4 << 2));
            #pragma unroll
            for (int kk = 0; kk < 4; ++kk) {
                float h = (kk == 0) ? hv.x : (kk == 1) ? hv.y : (kk == 2) ? hv.z : hv.w;
                const float4* wr = (const float4*)(W2 + (size_t)(k4 * 4 + kk) * 64 + s * 16);
                float4 wv0 = wr[0], wv1 = wr[1], wv2 = wr[2], wv3 = wr[3];
                sa[0]  = fmaf(h, wv0.x, sa[0]);  sa[1]  = fmaf(h, wv0.y, sa[1]);
                sa[2]  = fmaf(h, wv0.z, sa[2]);  sa[3]  = fmaf(h, wv0.w, sa[3]);
                sa[4]  = fmaf(h, wv1.x, sa[4]);  sa[5]  = fmaf(h, wv1.y, sa[5]);
                sa[6]  = fmaf(h, wv1.z, sa[6]);  sa[7]  = fmaf(h, wv1.w, sa[7]);
                sa[8]  = fmaf(h, wv2.x, sa[8]);  sa[9]  = fmaf(h, wv2.y, sa[9]);
                sa[10] = fmaf(h, wv2.z, sa[10]); sa[11] = fmaf(h, wv2.w, sa[11]);
                sa[12] = fmaf(h, wv3.x, sa[12]); sa[13] = fmaf(h, wv3.y, sa[13]);
                sa[14] = fmaf(h, wv3.z, sa[14]); sa[15] = fmaf(h, wv3.w, sa[15]);
            }
        }
        float* hb = h2s + (size_t)(wave * 16 + c) * 68 + s * 16;
        #pragma unroll
        for (int j4 = 0; j4 < 4; ++j4) {
            float4 rv;
            rv.x = fmaxf(sa[4 * j4 + 0], 0.f);
            rv.y = fmaxf(sa[4 * j4 + 1], 0.f);
            rv.z = fmaxf(sa[4 * j4 + 2], 0.f);
            rv.w = fmaxf(sa[4 * j4 + 3], 0.f);
            *(float4*)(hb + 4 * j4) = rv;
        }
    }
    asm volatile("s_waitcnt lgkmcnt(0)" ::: "memory");
    __builtin_amdgcn_sched_barrier(0);

    // ---- GEMM3 + output: lanes 0..31, ray rr = lane>>1, out-col = lane&1 ----
    if (lane < 32) {
        int rr = lane >> 1, cc2 = lane & 1;
        int lrow = wave * 16 + rr;
        const float* hr2 = h2s + (size_t)lrow * 68;
        float a = 0.f;
        #pragma unroll
        for (int i4 = 0; i4 < 16; ++i4) {
            float4 hv = *(const float4*)(hr2 + (i4 << 2));
            const float4* w3p = (const float4*)(W3 + (i4 << 3));
            float4 wa = w3p[0], wbv = w3p[1];
            if (cc2 == 0) {
                a = fmaf(hv.x, wa.x, a); a = fmaf(hv.y, wa.z, a);
                a = fmaf(hv.z, wbv.x, a); a = fmaf(hv.w, wbv.z, a);
            } else {
                a = fmaf(hv.x, wa.y, a); a = fmaf(hv.y, wa.w, a);
                a = fmaf(hv.z, wbv.y, a); a = fmaf(hv.w, wbv.w, a);
            }
        }
        if (cc2) {
            const float* o2p = orig + (size_t)(r0 + lrow) * 3;
            const float* e2p = endp + (size_t)(r0 + lrow) * 3;
            float dx = e2p[0] - o2p[0], dy = e2p[1] - o2p[1], dz = e2p[2] - o2p[2];
            a *= sqrtf(dx * dx + dy * dy + dz * dz);
        }
        out[((size_t)(r0 + lrow) << 1) + cc2] = a;
    }
}

extern "C" void kernel_launch(void* const* d_in, const int* in_sizes, int n_in,
                              void* d_out, int out_size, void* d_ws, size_t ws_size,
                              hipStream_t stream) {
    const float* orig = (const float*)d_in[0];
    const float* endp = (const float*)d_in[1];
    const int*   hist = (const int*)d_in[2];
    const float* nmin = (const float*)d_in[3];
    const float* next = (const float*)d_in[4];
    const float* emb  = (const float*)d_in[5];
    const float* W1   = (const float*)d_in[6];
    const float* W2   = (const float*)d_in[7];
    const float* W3   = (const float*)d_in[8];
    float* out = (float*)d_out;
    const int n_rays = in_sizes[0] / 3;
    dim3 grid(n_rays / RPB);

    const size_t w1t_bytes = (size_t)64 * 1024 * sizeof(unsigned short);  // 128 KB
    if (ws_size >= w1t_bytes && d_ws != nullptr) {
        unsigned short* W1T = (unsigned short*)d_ws;
        w1t_pre<<<dim3(32), dim3(256), 0, stream>>>(W1, W1T);
        nbvh_kernel<true><<<grid, THREADS, 0, stream>>>(orig, endp, hist, nmin, next,
                                                        emb, W1, W1T, W2, W3, out);
    } else {
        nbvh_kernel<false><<<grid, THREADS, 0, stream>>>(orig, endp, hist, nmin, next,
                                                         emb, W1, nullptr, W2, W3, out);
    }
}

// Round 6
// 514.036 us; speedup vs baseline: 1.1506x; 1.1506x over previous
//
#include <hip/hip_runtime.h>
#include <cstdint>

#define ENC_DEPTH 8
#define RPB 64
#define THREADS 256
#define WREG 8704   // bytes of LDS per wave: 8192 gather + (aliased h1/h2 in epilogue)

typedef __attribute__((ext_vector_type(8))) short bf16x8;
typedef __attribute__((ext_vector_type(4))) float f32x4;
union bf8u { bf16x8 v; unsigned u[4]; };

__device__ __forceinline__ unsigned cvtpk(float lo, float hi) {
    unsigned r;
    asm volatile("v_cvt_pk_bf16_f32 %0, %1, %2" : "=v"(r) : "v"(lo), "v"(hi));
    return r;
}
__device__ __forceinline__ float clamp01(float x) { return fminf(fmaxf(x, 0.f), 1.f); }

// global -> LDS direct DMA, 16B per lane; dest = uniform base + lane*16
#define GLL(gsrc, ldst) \
    __builtin_amdgcn_global_load_lds((__attribute__((address_space(1))) void*)(gsrc), \
                                     (__attribute__((address_space(3))) void*)(ldst), 16, 0, 0)

// Pre-pass: W1 f32 [1024][64] -> W1P bf16, lane-linear MFMA B-fragments:
// W1P[((d*4+kk)*4+nt)*64 + l] (bf16x8) = W1[d*128+kk*32+(l>>4)*8+j][nt*16+(l&15)]
__global__ void w1p_pre(const float* __restrict__ W1, unsigned short* __restrict__ W1P) {
    int tid = blockIdx.x * 256 + threadIdx.x;   // 8192 threads
    int l = tid & 63, nt = (tid >> 6) & 3, kk = (tid >> 8) & 3, dd = tid >> 10;
    int s = l >> 4, c = l & 15;
    const float* src = W1 + (size_t)(dd * 128 + kk * 32 + s * 8) * 64 + nt * 16 + c;
    bf8u r;
    #pragma unroll
    for (int j2 = 0; j2 < 4; ++j2)
        r.u[j2] = cvtpk(src[(2 * j2) * 64], src[(2 * j2 + 1) * 64]);
    *(bf16x8*)(W1P + (size_t)tid * 8) = r.v;
}

// Wave-autonomous, barrier-free. Per wave: 16 rays end-to-end.
// LDS per wave: corners f32 via global_load_lds, layout addr(k,q,c) = k*1024+q*256+c*16.
// vmcnt FIFO per iter (oldest->newest): gather(d) | nm/ex(d+1) | B(d) | gather(d+1).
// Waits: vmcnt(6) before A2 (gather(d) done, nm(d+1) live); MFMA B-wait = vmcnt(8)
// (compiler-counted; gather(d+1) survives). NEVER vmcnt(0) except last iter.
template<bool GW>
__global__ __launch_bounds__(THREADS, 3) void nbvh_kernel(
    const float* __restrict__ orig, const float* __restrict__ endp,
    const int* __restrict__ hist, const float* __restrict__ nodes_min,
    const float* __restrict__ nodes_extent, const float* __restrict__ emb,
    const float* __restrict__ W1, const unsigned short* __restrict__ W1P,
    const float* __restrict__ W2, const float* __restrict__ W3,
    float* __restrict__ out)
{
    __shared__ __align__(16) unsigned char lds_all[4 * WREG + 2048];
    int* hist_s = (int*)(lds_all + 4 * WREG);

    const int t = threadIdx.x;
    const int wave = t >> 6, lane = t & 63;
    const int c = lane & 15, s = lane >> 4;
    const int sh = s >> 1, h = s & 1;
    const int r0 = blockIdx.x * RPB;
    const int gray = r0 + wave * 16 + c;
    unsigned char* wcb = lds_all + wave * WREG;

    // ---- prologue: wave-private hist staging (lane -> 2 ints of one ray) ----
    {
        int ray_h = lane >> 2, dp = (lane & 3) << 1;
        int2 hv = *(const int2*)(hist + (size_t)(r0 + wave * 16 + ray_h) * ENC_DEPTH + dp);
        *(int2*)(hist_s + wave * 128 + ray_h * 8 + dp) = hv;
    }
    // oe in registers (4-lane broadcast)
    const float* opr = orig + (size_t)gray * 3;
    const float* epr = endp + (size_t)gray * 3;
    float oex = opr[0], oey = opr[1], oez = opr[2];
    float eex = epr[0], eey = epr[1], eez = epr[2];

    asm volatile("s_waitcnt lgkmcnt(0)" ::: "memory");
    __builtin_amdgcn_sched_barrier(0);

    // ---- gather(0) into LDS + nm/ex(0) into regs ----
    int node = hist_s[wave * 128 + c * 8 + 0];
    {
        const float* esrc = emb + ((size_t)node << 7) + (s << 2);
        #pragma unroll
        for (int j = 0; j < 8; ++j) GLL(esrc + (j << 4), wcb + (j << 10));
    }
    float nm0 = nodes_min[node * 3], nm1 = nodes_min[node * 3 + 1], nm2 = nodes_min[node * 3 + 2];
    float ex0 = nodes_extent[node * 3], ex1 = nodes_extent[node * 3 + 1], ex2 = nodes_extent[node * 3 + 2];

    f32x4 acc0 = {0.f,0.f,0.f,0.f}, acc1 = {0.f,0.f,0.f,0.f};
    f32x4 acc2 = {0.f,0.f,0.f,0.f}, acc3 = {0.f,0.f,0.f,0.f};

    const float tb = (float)sh * (1.0f / 7.0f);

    for (int d = 0; d < ENC_DEPTH; ++d) {
        // ---- issue nm/ex(d+1) (oldest-after-gather in FIFO), then counted wait ----
        float nn0 = nm0, nn1 = nm1, nn2 = nm2, en0 = ex0, en1 = ex1, en2 = ex2;
        int node1 = 0;
        if (d < ENC_DEPTH - 1) {
            node1 = hist_s[wave * 128 + c * 8 + d + 1];
            nn0 = nodes_min[node1 * 3]; nn1 = nodes_min[node1 * 3 + 1]; nn2 = nodes_min[node1 * 3 + 2];
            en0 = nodes_extent[node1 * 3]; en1 = nodes_extent[node1 * 3 + 1]; en2 = nodes_extent[node1 * 3 + 2];
            __builtin_amdgcn_sched_barrier(0);
            asm volatile("s_waitcnt vmcnt(6)" ::: "memory");   // gather(d) resident; nm(d+1) in flight
        } else {
            __builtin_amdgcn_sched_barrier(0);
            asm volatile("s_waitcnt vmcnt(0)" ::: "memory");
        }
        __builtin_amdgcn_sched_barrier(0);

        // ---- A2: weights for 4 points (p = 2i+sh), f-half h; corners f32 from LDS ----
        bf8u fr0, fr1, fr2, fr3;
        {
            float rx = __builtin_amdgcn_rcpf(ex0);
            float ry = __builtin_amdgcn_rcpf(ex1);
            float rz = __builtin_amdgcn_rcpf(ex2);
            float po0 = clamp01((oex - nm0) * rx);
            float po1 = clamp01((oey - nm1) * ry);
            float po2 = clamp01((oez - nm2) * rz);
            float pe0 = clamp01((eex - nm0) * rx);
            float pe1 = clamp01((eey - nm1) * ry);
            float pe2 = clamp01((eez - nm2) * rz);
            float d0 = pe0 - po0, d1 = pe1 - po1, d2 = pe2 - po2;

            float w[4][8];
            #pragma unroll
            for (int i = 0; i < 4; ++i) {
                float tt = tb + (float)(2 * i) * (1.0f / 7.0f);
                float x = po0 + d0 * tt, y = po1 + d1 * tt, z = po2 + d2 * tt;
                float ox = 1.f - x, oy = 1.f - y, oz = 1.f - z;
                float a0 = oy * oz, a1 = y * oz, a2 = oy * z, a3 = y * z;
                w[i][0] = ox * a0; w[i][1] = x * a0;
                w[i][2] = ox * a1; w[i][3] = ox * a2;
                w[i][4] = x * a2;  w[i][5] = ox * a3;
                w[i][6] = x * a1;  w[i][7] = x * a3;
            }
            float facc[4][8];
            #pragma unroll
            for (int i = 0; i < 4; ++i)
                #pragma unroll
                for (int f = 0; f < 8; ++f) facc[i][f] = 0.f;

            const unsigned char* cb = wcb + (h ? 512 : 0) + c * 16;
            #pragma unroll
            for (int k = 0; k < 8; ++k) {
                float4 ca = *(const float4*)(cb + k * 1024);
                float4 cbv = *(const float4*)(cb + k * 1024 + 256);
                #pragma unroll
                for (int i = 0; i < 4; ++i) {
                    float wk = w[i][k];
                    facc[i][0] = fmaf(wk, ca.x, facc[i][0]);
                    facc[i][1] = fmaf(wk, ca.y, facc[i][1]);
                    facc[i][2] = fmaf(wk, ca.z, facc[i][2]);
                    facc[i][3] = fmaf(wk, ca.w, facc[i][3]);
                    facc[i][4] = fmaf(wk, cbv.x, facc[i][4]);
                    facc[i][5] = fmaf(wk, cbv.y, facc[i][5]);
                    facc[i][6] = fmaf(wk, cbv.z, facc[i][6]);
                    facc[i][7] = fmaf(wk, cbv.w, facc[i][7]);
                }
            }
            #pragma unroll
            for (int j2 = 0; j2 < 4; ++j2) {
                fr0.u[j2] = cvtpk(facc[0][2*j2], facc[0][2*j2+1]);
                fr1.u[j2] = cvtpk(facc[1][2*j2], facc[1][2*j2+1]);
                fr2.u[j2] = cvtpk(facc[2][2*j2], facc[2][2*j2+1]);
                fr3.u[j2] = cvtpk(facc[3][2*j2], facc[3][2*j2+1]);
            }
        }
        __builtin_amdgcn_sched_barrier(0);

        // ---- B loads for depth d (issued BEFORE gather(d+1): MFMA wait stays counted) ----
        bf16x8 B[4][4];
        if constexpr (GW) {
            const unsigned short* wb = W1P + ((size_t)d * 16 * 64 + lane) * 8;
            #pragma unroll
            for (int kk = 0; kk < 4; ++kk)
                #pragma unroll
                for (int nt = 0; nt < 4; ++nt)
                    B[kk][nt] = *(const bf16x8*)(wb + (size_t)(kk * 4 + nt) * 64 * 8);
        } else {
            #pragma unroll
            for (int kk = 0; kk < 4; ++kk)
                #pragma unroll
                for (int nt = 0; nt < 4; ++nt) {
                    const float* src = W1 + (size_t)(d * 128 + kk * 32 + s * 8) * 64 + nt * 16 + c;
                    bf8u r;
                    #pragma unroll
                    for (int j2 = 0; j2 < 4; ++j2)
                        r.u[j2] = cvtpk(src[(2 * j2) * 64], src[(2 * j2 + 1) * 64]);
                    B[kk][nt] = r.v;
                }
        }
        __builtin_amdgcn_sched_barrier(0);

        // ---- gather(d+1) into same LDS region (A2(d) reads complete; newest in FIFO) ----
        if (d < ENC_DEPTH - 1) {
            const float* esrc = emb + ((size_t)node1 << 7) + (s << 2);
            #pragma unroll
            for (int j = 0; j < 8; ++j) GLL(esrc + (j << 4), wcb + (j << 10));
        }
        __builtin_amdgcn_sched_barrier(0);

        // ---- MFMA: all operands in registers; B-wait = vmcnt(8), gather survives ----
        __builtin_amdgcn_s_setprio(1);
        #pragma unroll
        for (int nt = 0; nt < 4; ++nt) {
            f32x4* ac = (nt == 0) ? &acc0 : (nt == 1) ? &acc1 : (nt == 2) ? &acc2 : &acc3;
            *ac = __builtin_amdgcn_mfma_f32_16x16x32_bf16(fr0.v, B[0][nt], *ac, 0, 0, 0);
            *ac = __builtin_amdgcn_mfma_f32_16x16x32_bf16(fr1.v, B[1][nt], *ac, 0, 0, 0);
            *ac = __builtin_amdgcn_mfma_f32_16x16x32_bf16(fr2.v, B[2][nt], *ac, 0, 0, 0);
            *ac = __builtin_amdgcn_mfma_f32_16x16x32_bf16(fr3.v, B[3][nt], *ac, 0, 0, 0);
        }
        __builtin_amdgcn_s_setprio(0);

        nm0 = nn0; nm1 = nn1; nm2 = nn2;
        ex0 = en0; ex1 = en1; ex2 = en2;
    }

    // ---- h1 = relu(GEMM1) -> wave-local LDS [16][68] f32 (aliases corner region) ----
    float* h1w = (float*)(lds_all + wave * WREG);
    {
        #pragma unroll
        for (int r = 0; r < 4; ++r) {
            h1w[(s * 4 + r) * 68 +  0 + c] = fmaxf(acc0[r], 0.f);
            h1w[(s * 4 + r) * 68 + 16 + c] = fmaxf(acc1[r], 0.f);
            h1w[(s * 4 + r) * 68 + 32 + c] = fmaxf(acc2[r], 0.f);
            h1w[(s * 4 + r) * 68 + 48 + c] = fmaxf(acc3[r], 0.f);
        }
    }
    asm volatile("s_waitcnt lgkmcnt(0)" ::: "memory");
    __builtin_amdgcn_sched_barrier(0);

    // ---- GEMM2: h2 = relu(h1 @ W2); lane: row c, cols [16s,16s+16); W2 L1-hot ----
    float* h2w = (float*)(lds_all + wave * WREG + 4352);
    {
        float sa[16];
        #pragma unroll
        for (int j = 0; j < 16; ++j) sa[j] = 0.f;
        const float* hr = h1w + c * 68;
        #pragma unroll
        for (int k4 = 0; k4 < 16; ++k4) {
            float4 hv = *(const float4*)(hr + (k4 << 2));
            #pragma unroll
            for (int kk = 0; kk < 4; ++kk) {
                float hval = (kk == 0) ? hv.x : (kk == 1) ? hv.y : (kk == 2) ? hv.z : hv.w;
                const float4* wr = (const float4*)(W2 + (size_t)(k4 * 4 + kk) * 64 + s * 16);
                float4 w0 = wr[0], w1 = wr[1], w2 = wr[2], w3 = wr[3];
                sa[0]  = fmaf(hval, w0.x, sa[0]);  sa[1]  = fmaf(hval, w0.y, sa[1]);
                sa[2]  = fmaf(hval, w0.z, sa[2]);  sa[3]  = fmaf(hval, w0.w, sa[3]);
                sa[4]  = fmaf(hval, w1.x, sa[4]);  sa[5]  = fmaf(hval, w1.y, sa[5]);
                sa[6]  = fmaf(hval, w1.z, sa[6]);  sa[7]  = fmaf(hval, w1.w, sa[7]);
                sa[8]  = fmaf(hval, w2.x, sa[8]);  sa[9]  = fmaf(hval, w2.y, sa[9]);
                sa[10] = fmaf(hval, w2.z, sa[10]); sa[11] = fmaf(hval, w2.w, sa[11]);
                sa[12] = fmaf(hval, w3.x, sa[12]); sa[13] = fmaf(hval, w3.y, sa[13]);
                sa[14] = fmaf(hval, w3.z, sa[14]); sa[15] = fmaf(hval, w3.w, sa[15]);
            }
        }
        float* hb = h2w + c * 68 + s * 16;
        #pragma unroll
        for (int j4 = 0; j4 < 4; ++j4) {
            float4 rv;
            rv.x = fmaxf(sa[4 * j4 + 0], 0.f);
            rv.y = fmaxf(sa[4 * j4 + 1], 0.f);
            rv.z = fmaxf(sa[4 * j4 + 2], 0.f);
            rv.w = fmaxf(sa[4 * j4 + 3], 0.f);
            *(float4*)(hb + 4 * j4) = rv;
        }
    }
    asm volatile("s_waitcnt lgkmcnt(0)" ::: "memory");
    __builtin_amdgcn_sched_barrier(0);

    // ---- GEMM3 + output ----
    if (lane < 32) {
        int rr = lane >> 1, cc2 = lane & 1;
        const float* hr2 = h2w + rr * 68;
        float a = 0.f;
        #pragma unroll
        for (int i4 = 0; i4 < 16; ++i4) {
            float4 hv = *(const float4*)(hr2 + (i4 << 2));
            const float4* w3p = (const float4*)(W3 + (i4 << 3));
            float4 wa = w3p[0], wbv = w3p[1];
            if (cc2 == 0) {
                a = fmaf(hv.x, wa.x, a); a = fmaf(hv.y, wa.z, a);
                a = fmaf(hv.z, wbv.x, a); a = fmaf(hv.w, wbv.z, a);
            } else {
                a = fmaf(hv.x, wa.y, a); a = fmaf(hv.y, wa.w, a);
                a = fmaf(hv.z, wbv.y, a); a = fmaf(hv.w, wbv.w, a);
            }
        }
        int orow = r0 + wave * 16 + rr;
        if (cc2) {
            const float* o2p = orig + (size_t)orow * 3;
            const float* e2p = endp + (size_t)orow * 3;
            float dx = e2p[0] - o2p[0], dy = e2p[1] - o2p[1], dz = e2p[2] - o2p[2];
            a *= sqrtf(dx * dx + dy * dy + dz * dz);
        }
        out[((size_t)orow << 1) + cc2] = a;
    }
}

extern "C" void kernel_launch(void* const* d_in, const int* in_sizes, int n_in,
                              void* d_out, int out_size, void* d_ws, size_t ws_size,
                              hipStream_t stream) {
    const float* orig = (const float*)d_in[0];
    const float* endp = (const float*)d_in[1];
    const int*   hist = (const int*)d_in[2];
    const float* nmin = (const float*)d_in[3];
    const float* next = (const float*)d_in[4];
    const float* emb  = (const float*)d_in[5];
    const float* W1   = (const float*)d_in[6];
    const float* W2   = (const float*)d_in[7];
    const float* W3   = (const float*)d_in[8];
    float* out = (float*)d_out;
    const int n_rays = in_sizes[0] / 3;
    dim3 grid(n_rays / RPB);

    const size_t w1p_bytes = (size_t)64 * 1024 * sizeof(unsigned short);  // 128 KB
    if (ws_size >= w1p_bytes && d_ws != nullptr) {
        unsigned short* W1P = (unsigned short*)d_ws;
        w1p_pre<<<dim3(32), dim3(256), 0, stream>>>(W1, W1P);
        nbvh_kernel<true><<<grid, THREADS, 0, stream>>>(orig, endp, hist, nmin, next,
                                                        emb, W1, W1P, W2, W3, out);
    } else {
        nbvh_kernel<false><<<grid, THREADS, 0, stream>>>(orig, endp, hist, nmin, next,
                                                         emb, W1, nullptr, W2, W3, out);
    }
}